// Round 3
// baseline (152.130 us; speedup 1.0000x reference)
//
#include <hip/hip_runtime.h>
#include <hip/hip_bf16.h>

#define B_   16
#define CIN  256
#define COUT 256
#define HH   64
#define WW   64
#define WDIM 512
#define OH   128
#define OW   128

#define LDK  264  // padded K stride in LDS (bf16 units)
#define YLP  72   // padded px stride for ylds (bf16 units)
#define MCH  32   // output channels per m-chunk

typedef __attribute__((ext_vector_type(8))) short short8;
typedef __attribute__((ext_vector_type(4))) float f32x4;

__device__ __forceinline__ unsigned short f2bf(float f) {
    __hip_bfloat16 h = __float2bfloat16(f);
    return *reinterpret_cast<unsigned short*>(&h);
}
__device__ __forceinline__ float bf2f(unsigned short u) {
    unsigned int t = ((unsigned int)u) << 16;
    return *reinterpret_cast<float*>(&t);
}

// ws layout: bytes [0..16640) float scratch (sumsq partials + styles)
//            byte 32768:  wb bf16 [16][256][256]   (2 MB)
//            byte 4 MiB:  y  bf16 [16][256][64][64] (33.5 MB)

__global__ __launch_bounds__(256) void k_styles(const float* __restrict__ w,
                                                const float* __restrict__ aw,
                                                const float* __restrict__ ab,
                                                float* __restrict__ ws) {
    int b = blockIdx.x, i = threadIdx.x;
    const float4* wr = (const float4*)(w + b * WDIM);
    const float4* ar = (const float4*)(aw + (size_t)i * WDIM);
    float acc = 0.f;
    #pragma unroll 4
    for (int k = 0; k < WDIM / 4; ++k) {
        float4 wv = wr[k], av = ar[k];
        acc += wv.x * av.x + wv.y * av.y + wv.z * av.z + wv.w * av.w;
    }
    const float wg = 0.04419417382415922f; // 1/sqrt(512)
    float st = acc * wg + ab[i];
    ws[64 + b * CIN + i] = st;
    __shared__ float sred[256];
    sred[i] = st * st;
    __syncthreads();
    for (int s = 128; s > 0; s >>= 1) {
        if (i < s) sred[i] += sred[i + s];
        __syncthreads();
    }
    if (i == 0) ws[b] = sred[0];
}

__global__ __launch_bounds__(64) void k_wb(const float* __restrict__ weight,
                                           const float* __restrict__ ws,
                                           unsigned short* __restrict__ wb) {
    int o = blockIdx.x, b = blockIdx.y, l = threadIdx.x;
    float tot = 0.f;
    #pragma unroll
    for (int j = 0; j < B_; ++j) tot += ws[j];
    float srs = rsqrtf(tot / (float)(B_ * CIN));
    float4 wk = *(const float4*)(weight + (size_t)o * CIN + l * 4);
    float ss = wk.x * wk.x + wk.y * wk.y + wk.z * wk.z + wk.w * wk.w;
    #pragma unroll
    for (int off = 32; off; off >>= 1) ss += __shfl_xor(ss, off);
    float wkn = rsqrtf(ss / (float)CIN);
    float4 st = *(const float4*)(ws + 64 + b * CIN + l * 4);
    float4 t;
    t.x = wk.x * wkn * st.x * srs;
    t.y = wk.y * wkn * st.y * srs;
    t.z = wk.z * wkn * st.z * srs;
    t.w = wk.w * wkn * st.w * srs;
    float s2 = t.x * t.x + t.y * t.y + t.z * t.z + t.w * t.w;
    #pragma unroll
    for (int off = 32; off; off >>= 1) s2 += __shfl_xor(s2, off);
    float dcoef = rsqrtf(s2 + 1e-8f);
    ushort4 pk;
    pk.x = f2bf(t.x * dcoef);
    pk.y = f2bf(t.y * dcoef);
    pk.z = f2bf(t.z * dcoef);
    pk.w = f2bf(t.w * dcoef);
    *(ushort4*)(wb + ((size_t)b * COUT + o) * CIN + l * 4) = pk;
}

// Conv kernel: block (r, b) handles input row r (64 px), all 256 out channels.
// Writes y bf16 [b][o][r][*]. LDS 38.4 KB -> 3 blocks/CU.
__global__ __launch_bounds__(512, 6) void k_conv(const float* __restrict__ x,
                                                 const float* __restrict__ bias,
                                                 const unsigned short* __restrict__ wb,
                                                 unsigned short* __restrict__ y) {
    __shared__ __align__(16) unsigned short xt[WW * LDK];    // 33792 B
    __shared__ __align__(16) unsigned short ylds[MCH * YLP]; // 4608 B
    const int r = blockIdx.x;
    const int b = blockIdx.y;
    const int tid = threadIdx.x;
    const int lane = tid & 63;

    // ---- stage row r: 64 px x 256 ch -> bf16 [px][K] ----
    {
        const int g = tid & 15;   // col group: cols g*4..g*4+3
        const int kk = tid >> 4;  // 0..31 -> channels kk*8..kk*8+7
        const float* xp = x + (size_t)b * CIN * HH * WW + r * WW + g * 4;
        float4 v[8];
        #pragma unroll
        for (int c = 0; c < 8; ++c)
            v[c] = *(const float4*)(xp + (size_t)(kk * 8 + c) * (HH * WW));
        #pragma unroll
        for (int j = 0; j < 4; ++j) {
            union { short8 s; unsigned short u[8]; } pk;
            #pragma unroll
            for (int c = 0; c < 8; ++c) {
                float f = (j == 0) ? v[c].x : (j == 1) ? v[c].y : (j == 2) ? v[c].z : v[c].w;
                pk.u[c] = f2bf(f);
            }
            *reinterpret_cast<short8*>(&xt[(g * 4 + j) * LDK + kk * 8]) = pk.s;
        }
    }
    __syncthreads();

    const int wv = tid >> 6;
    const int wm = wv & 1, wn = wv >> 1;  // 2 m-frags x 4 n-groups (4x16=64 px)
    const int n0 = wn * 16;
    const int hi = lane >> 4, lo = lane & 15;
    const unsigned short* wbp = wb + (size_t)b * COUT * CIN;

    for (int mc = 0; mc < COUT / MCH; ++mc) {
        const int m0 = mc * MCH + wm * 16;
        f32x4 acc = {0.f, 0.f, 0.f, 0.f};
        #pragma unroll
        for (int ks = 0; ks < 8; ++ks) {
            const int k0 = ks * 32;
            short8 a = *(const short8*)(wbp + (size_t)(m0 + lo) * CIN + k0 + hi * 8);
            short8 bx = *(const short8*)&xt[(n0 + lo) * LDK + k0 + hi * 8];
            acc = __builtin_amdgcn_mfma_f32_16x16x32_bf16(a, bx, acc, 0, 0, 0);
        }
        // D layout: col(px)=lane&15, row(m)=(lane>>4)*4+j
        const int mloc = wm * 16 + hi * 4;
        #pragma unroll
        for (int j = 0; j < 4; ++j) {
            float bs = bias[mc * MCH + mloc + j];
            ylds[(mloc + j) * YLP + n0 + lo] = f2bf(acc[j] + bs);
        }
        __syncthreads();
        // copy-out: 32 ch x 64 px, 8B/thread, coalesced
        {
            const int ch = tid >> 4, sub = tid & 15;
            ushort4 v4 = *(const ushort4*)&ylds[ch * YLP + sub * 4];
            *(ushort4*)(y + ((size_t)(b * COUT + mc * MCH + ch) * (HH * WW)) + r * WW + sub * 4) = v4;
        }
        __syncthreads();
    }
}

// Upsample kernel: half-wave (32 lanes) per (b, ch, p): reads y rows p-1,p,p+1,
// writes out rows 2p, 2p+1 (full 128 cols). No LDS, no barriers.
__global__ __launch_bounds__(256, 8) void k_up(const unsigned short* __restrict__ y,
                                               float* __restrict__ out) {
    const int tid = threadIdx.x;
    const int t = tid & 31;       // col quad
    const int s = tid >> 5;       // task slot 0..7
    const int idx = blockIdx.x * 8 + s;
    const int p = idx & 63;
    const int ch = (idx >> 6) & 255;
    const int b = idx >> 14;

    const unsigned short* yb = y + (size_t)(b * COUT + ch) * (HH * WW);
    const int pm1 = max(p - 1, 0), pp1 = min(p + 1, HH - 1);
    unsigned int T = *(const unsigned int*)(yb + pm1 * WW + 2 * t);
    unsigned int M = *(const unsigned int*)(yb + p   * WW + 2 * t);
    unsigned int Bt = *(const unsigned int*)(yb + pp1 * WW + 2 * t);

    float tB = bf2f((unsigned short)(T & 0xffff)), tC = bf2f((unsigned short)(T >> 16));
    float mB = bf2f((unsigned short)(M & 0xffff)), mC = bf2f((unsigned short)(M >> 16));
    float bB = bf2f((unsigned short)(Bt & 0xffff)), bC = bf2f((unsigned short)(Bt >> 16));

    // row-interp: out row 2p   = 0.25*y[p-1] + 0.75*y[p]
    //             out row 2p+1 = 0.75*y[p]   + 0.25*y[p+1]
    float aB = 0.25f * tB + 0.75f * mB, aC = 0.25f * tC + 0.75f * mC;
    float eB = 0.75f * mB + 0.25f * bB, eC = 0.75f * mC + 0.25f * bC;

    // neighbor cols via shfl within 32-lane group
    float aA = __shfl_up(aC, 1, 32);  if (t == 0)  aA = aB;
    float aD = __shfl_down(aB, 1, 32); if (t == 31) aD = aC;
    float eA = __shfl_up(eC, 1, 32);  if (t == 0)  eA = eB;
    float eD = __shfl_down(eB, 1, 32); if (t == 31) eD = eC;

    float4 o0, o1;
    o0.x = 0.25f * aA + 0.75f * aB;
    o0.y = 0.75f * aB + 0.25f * aC;
    o0.z = 0.25f * aB + 0.75f * aC;
    o0.w = 0.75f * aC + 0.25f * aD;
    o1.x = 0.25f * eA + 0.75f * eB;
    o1.y = 0.75f * eB + 0.25f * eC;
    o1.z = 0.25f * eB + 0.75f * eC;
    o1.w = 0.75f * eC + 0.25f * eD;

    float* op = out + (size_t)(b * COUT + ch) * (OH * OW) + (2 * p) * OW + 4 * t;
    *(float4*)op = o0;
    *(float4*)(op + OW) = o1;
}

extern "C" void kernel_launch(void* const* d_in, const int* in_sizes, int n_in,
                              void* d_out, int out_size, void* d_ws, size_t ws_size,
                              hipStream_t stream) {
    (void)in_sizes; (void)n_in; (void)out_size; (void)ws_size;
    const float* x      = (const float*)d_in[0];
    const float* w      = (const float*)d_in[1];
    const float* aw     = (const float*)d_in[2];
    const float* ab     = (const float*)d_in[3];
    const float* weight = (const float*)d_in[4];
    const float* bias   = (const float*)d_in[5];
    float* out = (float*)d_out;
    float* wsf = (float*)d_ws;
    unsigned short* wb = (unsigned short*)((char*)d_ws + 32768);
    unsigned short* y  = (unsigned short*)((char*)d_ws + (4u << 20));

    hipLaunchKernelGGL(k_styles, dim3(16), dim3(256), 0, stream, w, aw, ab, wsf);
    hipLaunchKernelGGL(k_wb, dim3(COUT, B_), dim3(64), 0, stream, weight, wsf, wb);
    hipLaunchKernelGGL(k_conv, dim3(HH, B_), dim3(512), 0, stream, x, bias, wb, y);
    hipLaunchKernelGGL(k_up, dim3(B_ * COUT * HH / 8), dim3(256), 0, stream, y, out);
}